// Round 7
// baseline (2574.838 us; speedup 1.0000x reference)
//
#include <hip/hip_runtime.h>
#include <hip/hip_fp16.h>

#define D 64
#define NKR 16
#define NB 1024
#define NL 8

typedef __attribute__((ext_vector_type(8))) _Float16 half8;
typedef __attribute__((ext_vector_type(16))) float f32x16;
typedef __attribute__((ext_vector_type(4))) int i32x4;

static __device__ __forceinline__ half8 neg8(half8 x) {
    i32x4 u = __builtin_bit_cast(i32x4, x);
    u = u ^ (int)0x80008000;
    return __builtin_bit_cast(half8, u);
}

static __device__ __forceinline__ unsigned pkrtz(float a, float b) {
    auto h = __builtin_amdgcn_cvt_pkrtz(a, b);   // __fp16 ext_vector_type(2)
    return __builtin_bit_cast(unsigned, h);
}

// v_permlane32_swap_b32: a.row1 <-> b.row0 (row = 32-lane half).
static __device__ __forceinline__ void plswap(unsigned &a, unsigned &b) {
    asm volatile("v_permlane32_swap_b32 %0, %1" : "+v"(a), "+v"(b));
}

union Pack4 { _Float16 h[4]; uint2 u; };
union H8 { unsigned u[4]; uint2 v[2]; half8 h; };

#define MFMA __builtin_amdgcn_mfma_f32_32x32x16_f16

// ---------------------------------------------------------------------------
// Fragment-order layout for 64x64 f16 matrices (both kraus and rho^T):
//   element (row, col) -> ihalf*2048 + (2*(col>>4) + ((col>>3)&1))*256 + (row&31)*8 + (col&7)
//   with ihalf = row>>5.  A wave's MFMA fragment (ks) for half ih is then ONE fully
//   coalesced 16B/lane load at: base + ih*2048 + ks*512 + lane*8   (halves).
// ---------------------------------------------------------------------------

// kraus fp32 -> fp16 fragment order: [L*K][plane][ihalf][slot][l31][8]
__global__ void kconv_kernel(const float* __restrict__ re, const float* __restrict__ im,
                             _Float16* __restrict__ out) {
    int plane = blockIdx.y;
    int idx = blockIdx.x * blockDim.x + threadIdx.x;
    const float* src = plane ? im : re;
    float4 v = ((const float4*)src)[idx];
    int e = idx * 4;
    int lk = e >> 12;
    int rem = e & 4095;
    int row = rem >> 6, col = rem & 63;          // col multiple of 4
    int ihalf = row >> 5, r31 = row & 31;
    int ks = col >> 4, hl2 = (col >> 3) & 1, c = col & 7;   // c in {0,4}
    Pack4 p;
    p.h[0] = (_Float16)v.x; p.h[1] = (_Float16)v.y;
    p.h[2] = (_Float16)v.z; p.h[3] = (_Float16)v.w;
    size_t off = (size_t)(lk * 2 + plane) * 4096 + ihalf * 2048
               + (2 * ks + hl2) * 256 + r31 * 8 + c;
    *(uint2*)(out + off) = p.u;
}

// state fp32 -> fp16, rho^T in fragment order: out[b][plane][fragment-layout of rho^T]
__global__ void sconv_kernel(const float* __restrict__ re, const float* __restrict__ im,
                             _Float16* __restrict__ out) {
    __shared__ float tile[64][65];
    int b = blockIdx.x;
    int t = threadIdx.x;
    for (int plane = 0; plane < 2; ++plane) {
        const float* src = (plane ? im : re) + (size_t)b * 4096;
        __syncthreads();
        #pragma unroll
        for (int i = 0; i < 16; ++i) {
            int e = t + 256 * i;
            tile[e >> 6][e & 63] = src[e];          // tile[i][j] = state[i][j]
        }
        __syncthreads();
        _Float16* o = out + ((size_t)b * 2 + plane) * 4096;
        #pragma unroll
        for (int i = 0; i < 16; ++i) {
            int oi = t + 256 * i;
            int lh = oi >> 11, slot = (oi >> 8) & 7, r = (oi >> 3) & 31, c = oi & 7;
            int col = 16 * (slot >> 1) + 8 * (slot & 1) + c;
            int row = 32 * lh + r;
            o[oi] = (_Float16)tile[col][row];       // rho^T[row][col] = state[col][row]
        }
    }
}

// Stage-1 f32x16 tile (lane=col i, reg 4g+j -> row l_rel=8g+4hl+j) -> two stage-2
// A-fragments (lane=row i, halves l_rel 16c+8hl+0..7) in registers: 8 cvt + 4 permlane.
static __device__ __forceinline__ void exchange(const f32x16 &dd, half8 &f0, half8 &f1) {
    unsigned A0 = pkrtz(dd[0],  dd[1]),  B0 = pkrtz(dd[2],  dd[3]);
    unsigned A1 = pkrtz(dd[4],  dd[5]),  B1 = pkrtz(dd[6],  dd[7]);
    unsigned A2 = pkrtz(dd[8],  dd[9]),  B2 = pkrtz(dd[10], dd[11]);
    unsigned A3 = pkrtz(dd[12], dd[13]), B3 = pkrtz(dd[14], dd[15]);
    plswap(A0, A1);
    plswap(B0, B1);
    plswap(A2, A3);
    plswap(B2, B3);
    H8 h0; h0.u[0] = A0; h0.u[1] = B0; h0.u[2] = A1; h0.u[3] = B1; f0 = h0.h;
    H8 h1; h1.u[0] = A2; h1.u[1] = B2; h1.u[2] = A3; h1.u[3] = B3; f1 = h1.h;
}

// One kraus step, all operands from global (L1/L2-resident K, fragment-order layout).
// Interleaved: stage1(lh) -> exchange -> stage2 slices 2lh,2lh+1 (both m-tiles), so
// dd and af live ranges stay short. 64 MFMAs, 16 coalesced dwordx4 loads, no LDS.
template<int IT>
static __device__ __forceinline__ void kstep(
    const _Float16* __restrict__ kb,     // this k: [plane][ihalf][slot][l31][8]
    const half8 (&a1re)[2][4], const half8 (&a1im)[2][4],
    f32x16 (&accRe)[2], f32x16 (&accIm)[2],
    int lane)
{
    const _Float16* bo = kb + IT * 2048;          // own half (stage1 B + stage2 mt=IT)
    const _Float16* bx = kb + (1 - IT) * 2048;    // other half (stage2 mt=1-IT)

    half8 bre[4], bim[4];
    #pragma unroll
    for (int ks = 0; ks < 4; ++ks) {
        bre[ks] = *(const half8*)(bo + ks * 512 + lane * 8);
        bim[ks] = *(const half8*)(bo + 4096 + ks * 512 + lane * 8);
    }

    #pragma unroll
    for (int lh = 0; lh < 2; ++lh) {
        f32x16 ddre, ddim;
        #pragma unroll
        for (int i = 0; i < 16; ++i) { ddre[i] = 0.f; ddim[i] = 0.f; }
        __builtin_amdgcn_s_setprio(1);
        #pragma unroll
        for (int ks = 0; ks < 4; ++ks) {
            half8 bn = neg8(bim[ks]);
            ddre = MFMA(a1re[lh][ks], bre[ks], ddre, 0, 0, 0);
            ddre = MFMA(a1im[lh][ks], bn,      ddre, 0, 0, 0);
            ddim = MFMA(a1re[lh][ks], bim[ks], ddim, 0, 0, 0);
            ddim = MFMA(a1im[lh][ks], bre[ks], ddim, 0, 0, 0);
        }
        __builtin_amdgcn_s_setprio(0);

        // other-half B for this lh's two l-slices: issue before exchange (latency hides)
        half8 br2[2], bi2[2];
        #pragma unroll
        for (int c = 0; c < 2; ++c) {
            const int ks = 2 * lh + c;
            br2[c] = *(const half8*)(bx + ks * 512 + lane * 8);
            bi2[c] = *(const half8*)(bx + 4096 + ks * 512 + lane * 8);
        }

        half8 fre0, fre1, fim0, fim1;
        exchange(ddre, fre0, fre1);
        exchange(ddim, fim0, fim1);

        #pragma unroll
        for (int c = 0; c < 2; ++c) {
            const int ks = 2 * lh + c;
            half8 afre = c ? fre1 : fre0;
            half8 afim = c ? fim1 : fim0;
            half8 an  = neg8(afre);
            __builtin_amdgcn_s_setprio(1);
            accRe[IT]     = MFMA(afre, bre[ks], accRe[IT], 0, 0, 0);
            accRe[IT]     = MFMA(afim, bim[ks], accRe[IT], 0, 0, 0);
            accIm[IT]     = MFMA(afim, bre[ks], accIm[IT], 0, 0, 0);
            accIm[IT]     = MFMA(an,   bim[ks], accIm[IT], 0, 0, 0);
            accRe[1 - IT] = MFMA(afre, br2[c],  accRe[1 - IT], 0, 0, 0);
            accRe[1 - IT] = MFMA(afim, bi2[c],  accRe[1 - IT], 0, 0, 0);
            accIm[1 - IT] = MFMA(afim, br2[c],  accIm[1 - IT], 0, 0, 0);
            accIm[1 - IT] = MFMA(an,   bi2[c],  accIm[1 - IT], 0, 0, 0);  // Im -= Tre*Kim
            __builtin_amdgcn_s_setprio(0);
        }
    }
}

template<int IT>
static __device__ __forceinline__ void run_layer(
    const _Float16* __restrict__ kraus,   // base of this wave's k-range
    const half8 (&a1re)[2][4], const half8 (&a1im)[2][4],
    f32x16 (&accRe)[2], f32x16 (&accIm)[2],
    int lane)
{
    #pragma unroll 1
    for (int k = 0; k < NKR / 2; ++k)
        kstep<IT>(kraus + (size_t)k * 8192, a1re, a1im, accRe, accIm, lane);
}

// Block = 128 threads = 2 waves; wave kh handles kraus k in [8kh, 8kh+8).
// Grid (NB, 2) -> 4096 waves = 4 waves/SIMD (VGPR<=128 via launch_bounds).
// Partial accumulators reduced once per layer through 16 KB LDS (1 barrier total).
__global__ __launch_bounds__(128, 4) void layer_kernel(
    const _Float16* __restrict__ rho_in,    // fragment-order rho^T, [b][plane][4096]
    _Float16* __restrict__ rho_out,
    float* __restrict__ final_out,
    const _Float16* __restrict__ kraus,     // this layer, fragment order: [K][plane][4096]
    int last)
{
    __shared__ float red[64][64];           // 16 KB: [value][lane], conflict-free

    const int b    = blockIdx.x;
    const int IT   = blockIdx.y;
    const int t    = threadIdx.x;
    const int kh   = t >> 6;                // k-half this wave owns
    const int lane = t & 63;
    const int l31  = lane & 31;
    const int hl   = lane >> 5;

    // ---- hoisted A1: full rho^T fragments (coalesced in fragment layout) ----
    half8 a1re[2][4], a1im[2][4];
    {
        const _Float16* rb = rho_in + (size_t)b * 2 * D * D;
        #pragma unroll
        for (int lh = 0; lh < 2; ++lh)
            #pragma unroll
            for (int ks = 0; ks < 4; ++ks) {
                a1re[lh][ks] = *(const half8*)(rb + lh * 2048 + ks * 512 + lane * 8);
                a1im[lh][ks] = *(const half8*)(rb + 4096 + lh * 2048 + ks * 512 + lane * 8);
            }
    }

    f32x16 accRe[2], accIm[2];
    #pragma unroll
    for (int mt = 0; mt < 2; ++mt)
        #pragma unroll
        for (int i = 0; i < 16; ++i) { accRe[mt][i] = 0.f; accIm[mt][i] = 0.f; }

    const _Float16* kbase = kraus + (size_t)kh * (NKR / 2) * 8192;
    if (IT == 0) run_layer<0>(kbase, a1re, a1im, accRe, accIm, lane);
    else         run_layer<1>(kbase, a1re, a1im, accRe, accIm, lane);

    // ---- reduce kh=1 partials into kh=0 via LDS (one barrier per layer) ----
    if (kh == 1) {
        #pragma unroll
        for (int mt = 0; mt < 2; ++mt)
            #pragma unroll
            for (int i = 0; i < 16; ++i) {
                red[mt * 32 + i][lane]      = accRe[mt][i];
                red[mt * 32 + 16 + i][lane] = accIm[mt][i];
            }
    }
    __syncthreads();
    if (kh == 0) {
        #pragma unroll
        for (int mt = 0; mt < 2; ++mt)
            #pragma unroll
            for (int i = 0; i < 16; ++i) {
                accRe[mt][i] += red[mt * 32 + i][lane];
                accIm[mt][i] += red[mt * 32 + 16 + i][lane];
            }

        // ---- epilogue: acc lane=col m_rel, reg 4g+j -> row i = 32*IT+8g+4hl+j ----
        if (!last) {
            // rho_new^T in fragment order: row=m=32mt+l31, col=i
            _Float16* ob = rho_out + (size_t)b * 2 * D * D;
            #pragma unroll
            for (int mt = 0; mt < 2; ++mt) {
                #pragma unroll
                for (int g = 0; g < 4; ++g) {
                    Pack4 pr, pi;
                    #pragma unroll
                    for (int j = 0; j < 4; ++j) {
                        pr.h[j] = (_Float16)accRe[mt][4 * g + j];
                        pi.h[j] = (_Float16)accIm[mt][4 * g + j];
                    }
                    const int off = mt * 2048 + (4 * IT + g) * 256 + l31 * 8 + 4 * hl;
                    *(uint2*)(ob + off)        = pr.u;
                    *(uint2*)(ob + 4096 + off) = pi.u;
                }
            }
        } else {
            float* o0 = final_out + (size_t)b * 4096;            // [0][b][i][m]
            float* o1 = final_out + (size_t)(NB + b) * 4096;     // [1][b][i][m]
            #pragma unroll
            for (int mt = 0; mt < 2; ++mt) {
                const int m = 32 * mt + l31;
                #pragma unroll
                for (int g = 0; g < 4; ++g) {
                    #pragma unroll
                    for (int j = 0; j < 4; ++j) {
                        const int i = 32 * IT + 8 * g + 4 * hl + j;
                        o0[i * D + m] = accRe[mt][4 * g + j];
                        o1[i * D + m] = accIm[mt][4 * g + j];
                    }
                }
            }
        }
    }
}

extern "C" void kernel_launch(void* const* d_in, const int* in_sizes, int n_in,
                              void* d_out, int out_size, void* d_ws, size_t ws_size,
                              hipStream_t stream) {
    const float* state_re = (const float*)d_in[0];
    const float* state_im = (const float*)d_in[1];
    const float* kraus_re = (const float*)d_in[2];
    const float* kraus_im = (const float*)d_in[3];

    _Float16* kraus_h = (_Float16*)d_ws;                         // 2 MB in ws (frag order)
    // ping-pong rho buffers live inside d_out (2 x 16 MB = out_size exactly).
    _Float16* bufA = (_Float16*)d_out;
    _Float16* bufB = (_Float16*)((char*)d_out + (size_t)NB * 2 * D * D * sizeof(_Float16));
    float* fout = (float*)d_out;

    kconv_kernel<<<dim3(512, 2), 256, 0, stream>>>(kraus_re, kraus_im, kraus_h);
    sconv_kernel<<<NB, 256, 0, stream>>>(state_re, state_im, bufA);

    for (int l = 0; l < NL; ++l) {
        const _Float16* in = (l & 1) ? bufB : bufA;
        _Float16* out      = (l & 1) ? bufA : bufB;
        layer_kernel<<<dim3(NB, 2), 128, 0, stream>>>(in, out, fout,
                                                      kraus_h + (size_t)l * NKR * 2 * D * D,
                                                      (l == NL - 1) ? 1 : 0);
    }
}

// Round 8
// 687.988 us; speedup vs baseline: 3.7426x; 3.7426x over previous
//
#include <hip/hip_runtime.h>
#include <hip/hip_fp16.h>

#define D 64
#define NKR 16
#define NB 1024
#define NL 8

typedef __attribute__((ext_vector_type(8))) _Float16 half8;
typedef __attribute__((ext_vector_type(16))) float f32x16;
typedef __attribute__((ext_vector_type(4))) int i32x4;

static __device__ __forceinline__ half8 neg8(half8 x) {
    i32x4 u = __builtin_bit_cast(i32x4, x);
    u = u ^ (int)0x80008000;
    return __builtin_bit_cast(half8, u);
}

static __device__ __forceinline__ unsigned pkrtz(float a, float b) {
    auto h = __builtin_amdgcn_cvt_pkrtz(a, b);   // __fp16 ext_vector_type(2)
    return __builtin_bit_cast(unsigned, h);
}

// v_permlane32_swap_b32: a.row1 <-> b.row0 (row = 32-lane half).
static __device__ __forceinline__ void plswap(unsigned &a, unsigned &b) {
    asm volatile("v_permlane32_swap_b32 %0, %1" : "+v"(a), "+v"(b));
}

union Pack4 { _Float16 h[4]; uint2 u; };
union H8 { unsigned u[4]; uint2 v[2]; half8 h; };

#define MFMA __builtin_amdgcn_mfma_f32_32x32x16_f16

// ---------------------------------------------------------------------------
// Fragment-order layout for 64x64 f16 matrices (both kraus and rho^T):
//   element (row, col) -> ihalf*2048 + (2*(col>>4) + ((col>>3)&1))*256 + (row&31)*8 + (col&7)
//   with ihalf = row>>5.  A wave's MFMA fragment (ks) for half ih is then ONE fully
//   coalesced 16B/lane load at: base + ih*2048 + ks*512 + lane*8   (halves).
// ---------------------------------------------------------------------------

// kraus fp32 -> fp16 fragment order: [L*K][plane][ihalf][slot][l31][8]
__global__ void kconv_kernel(const float* __restrict__ re, const float* __restrict__ im,
                             _Float16* __restrict__ out) {
    int plane = blockIdx.y;
    int idx = blockIdx.x * blockDim.x + threadIdx.x;
    const float* src = plane ? im : re;
    float4 v = ((const float4*)src)[idx];
    int e = idx * 4;
    int lk = e >> 12;
    int rem = e & 4095;
    int row = rem >> 6, col = rem & 63;          // col multiple of 4
    int ihalf = row >> 5, r31 = row & 31;
    int ks = col >> 4, hl2 = (col >> 3) & 1, c = col & 7;   // c in {0,4}
    Pack4 p;
    p.h[0] = (_Float16)v.x; p.h[1] = (_Float16)v.y;
    p.h[2] = (_Float16)v.z; p.h[3] = (_Float16)v.w;
    size_t off = (size_t)(lk * 2 + plane) * 4096 + ihalf * 2048
               + (2 * ks + hl2) * 256 + r31 * 8 + c;
    *(uint2*)(out + off) = p.u;
}

// state fp32 -> fp16, rho^T in fragment order: out[b][plane][fragment-layout of rho^T]
__global__ void sconv_kernel(const float* __restrict__ re, const float* __restrict__ im,
                             _Float16* __restrict__ out) {
    __shared__ float tile[64][65];
    int b = blockIdx.x;
    int t = threadIdx.x;
    for (int plane = 0; plane < 2; ++plane) {
        const float* src = (plane ? im : re) + (size_t)b * 4096;
        __syncthreads();
        #pragma unroll
        for (int i = 0; i < 16; ++i) {
            int e = t + 256 * i;
            tile[e >> 6][e & 63] = src[e];          // tile[i][j] = state[i][j]
        }
        __syncthreads();
        _Float16* o = out + ((size_t)b * 2 + plane) * 4096;
        #pragma unroll
        for (int i = 0; i < 16; ++i) {
            int oi = t + 256 * i;
            int lh = oi >> 11, slot = (oi >> 8) & 7, r = (oi >> 3) & 31, c = oi & 7;
            int col = 16 * (slot >> 1) + 8 * (slot & 1) + c;
            int row = 32 * lh + r;
            o[oi] = (_Float16)tile[col][row];       // rho^T[row][col] = state[col][row]
        }
    }
}

// Stage-1 f32x16 tile (lane=col i, reg 4g+j -> row l_rel=8g+4hl+j) -> two stage-2
// A-fragments (lane=row i, halves l_rel 16c+8hl+0..7) in registers: 8 cvt + 4 permlane.
static __device__ __forceinline__ void exchange(const f32x16 &dd, half8 &f0, half8 &f1) {
    unsigned A0 = pkrtz(dd[0],  dd[1]),  B0 = pkrtz(dd[2],  dd[3]);
    unsigned A1 = pkrtz(dd[4],  dd[5]),  B1 = pkrtz(dd[6],  dd[7]);
    unsigned A2 = pkrtz(dd[8],  dd[9]),  B2 = pkrtz(dd[10], dd[11]);
    unsigned A3 = pkrtz(dd[12], dd[13]), B3 = pkrtz(dd[14], dd[15]);
    plswap(A0, A1);
    plswap(B0, B1);
    plswap(A2, A3);
    plswap(B2, B3);
    H8 h0; h0.u[0] = A0; h0.u[1] = B0; h0.u[2] = A1; h0.u[3] = B1; f0 = h0.h;
    H8 h1; h1.u[0] = A2; h1.u[1] = B2; h1.u[2] = A3; h1.u[3] = B3; f1 = h1.h;
}

// Load the 8 "own-half" B fragments (stage1 B + stage2 mt=IT) for one kraus.
static __device__ __forceinline__ void loadbo(const _Float16* __restrict__ bo,
                                              half8 (&bre)[4], half8 (&bim)[4], int lane) {
    #pragma unroll
    for (int ks = 0; ks < 4; ++ks) {
        bre[ks] = *(const half8*)(bo + ks * 512 + lane * 8);
        bim[ks] = *(const half8*)(bo + 4096 + ks * 512 + lane * 8);
    }
}

// Compute one kraus step given pre-loaded own-half fragments (bre/bim, prefetched a
// full compute-phase ahead by the caller). Other-half (bx) fragments are issued at the
// top of each lh so the 16-MFMA stage-1 cluster covers their L1/L2 latency.
template<int IT>
static __device__ __forceinline__ void compute_k(
    const _Float16* __restrict__ kb,     // this k: [plane][ihalf][slot][l31][8]
    const half8 (&bre)[4], const half8 (&bim)[4],
    const half8 (&a1re)[2][4], const half8 (&a1im)[2][4],
    f32x16 (&accRe)[2], f32x16 (&accIm)[2],
    int lane)
{
    const _Float16* bx = kb + (1 - IT) * 2048;    // other half (stage2 mt=1-IT)

    #pragma unroll
    for (int lh = 0; lh < 2; ++lh) {
        // bx loads for this lh's two l-slices, issued BEFORE stage1 (hidden under it)
        half8 br2[2], bi2[2];
        #pragma unroll
        for (int c = 0; c < 2; ++c) {
            const int ks = 2 * lh + c;
            br2[c] = *(const half8*)(bx + ks * 512 + lane * 8);
            bi2[c] = *(const half8*)(bx + 4096 + ks * 512 + lane * 8);
        }

        f32x16 ddre, ddim;
        #pragma unroll
        for (int i = 0; i < 16; ++i) { ddre[i] = 0.f; ddim[i] = 0.f; }
        __builtin_amdgcn_s_setprio(1);
        #pragma unroll
        for (int ks = 0; ks < 4; ++ks) {
            half8 bn = neg8(bim[ks]);
            ddre = MFMA(a1re[lh][ks], bre[ks], ddre, 0, 0, 0);
            ddre = MFMA(a1im[lh][ks], bn,      ddre, 0, 0, 0);
            ddim = MFMA(a1re[lh][ks], bim[ks], ddim, 0, 0, 0);
            ddim = MFMA(a1im[lh][ks], bre[ks], ddim, 0, 0, 0);
        }
        __builtin_amdgcn_s_setprio(0);

        half8 fre0, fre1, fim0, fim1;
        exchange(ddre, fre0, fre1);
        exchange(ddim, fim0, fim1);

        #pragma unroll
        for (int c = 0; c < 2; ++c) {
            const int ks = 2 * lh + c;
            half8 afre = c ? fre1 : fre0;
            half8 afim = c ? fim1 : fim0;
            half8 an  = neg8(afre);
            __builtin_amdgcn_s_setprio(1);
            accRe[IT]     = MFMA(afre, bre[ks], accRe[IT], 0, 0, 0);
            accRe[IT]     = MFMA(afim, bim[ks], accRe[IT], 0, 0, 0);
            accIm[IT]     = MFMA(afim, bre[ks], accIm[IT], 0, 0, 0);
            accIm[IT]     = MFMA(an,   bim[ks], accIm[IT], 0, 0, 0);
            accRe[1 - IT] = MFMA(afre, br2[c],  accRe[1 - IT], 0, 0, 0);
            accRe[1 - IT] = MFMA(afim, bi2[c],  accRe[1 - IT], 0, 0, 0);
            accIm[1 - IT] = MFMA(afim, br2[c],  accIm[1 - IT], 0, 0, 0);
            accIm[1 - IT] = MFMA(an,   bi2[c],  accIm[1 - IT], 0, 0, 0);  // Im -= Tre*Kim
            __builtin_amdgcn_s_setprio(0);
        }
    }
}

// k-loop unrolled by 2 with named A/B own-half buffers (static indexing): the next
// kraus's 8 bo-loads are issued before the current compute, so they have an entire
// compute phase (~2000 cyc) to land. Last prefetch is clamped (redundant, harmless).
template<int IT>
static __device__ __forceinline__ void run_layer(
    const _Float16* __restrict__ kraus,
    const half8 (&a1re)[2][4], const half8 (&a1im)[2][4],
    f32x16 (&accRe)[2], f32x16 (&accIm)[2],
    int lane)
{
    const int boff = IT * 2048;
    half8 bAre[4], bAim[4], bBre[4], bBim[4];
    loadbo(kraus + boff, bAre, bAim, lane);
    #pragma unroll 1
    for (int kk = 0; kk < NKR / 2; ++kk) {
        const _Float16* kb0 = kraus + (size_t)(2 * kk) * 8192;
        loadbo(kb0 + 8192 + boff, bBre, bBim, lane);               // prefetch k = 2kk+1
        compute_k<IT>(kb0, bAre, bAim, a1re, a1im, accRe, accIm, lane);
        const _Float16* kb2 = (kk < NKR / 2 - 1) ? kb0 + 2 * 8192 : kb0;
        loadbo(kb2 + boff, bAre, bAim, lane);                      // prefetch k = 2kk+2
        compute_k<IT>(kb0 + 8192, bBre, bBim, a1re, a1im, accRe, accIm, lane);
    }
}

// One wave per block; grid (NB, 2): blockIdx.x = rho, blockIdx.y = output i-tile.
// No LDS, no barriers: 2048 free-running waves, K fragments read coalesced from L1/L2.
__global__ __launch_bounds__(64, 2) void layer_kernel(
    const _Float16* __restrict__ rho_in,    // fragment-order rho^T, [b][plane][4096]
    _Float16* __restrict__ rho_out,
    float* __restrict__ final_out,
    const _Float16* __restrict__ kraus,     // this layer, fragment order: [K][plane][4096]
    int last)
{
    const int b    = blockIdx.x;
    const int IT   = blockIdx.y;
    const int lane = threadIdx.x;
    const int l31  = lane & 31;
    const int hl   = lane >> 5;

    // ---- hoisted A1: full rho^T fragments (coalesced in fragment layout) ----
    half8 a1re[2][4], a1im[2][4];
    {
        const _Float16* rb = rho_in + (size_t)b * 2 * D * D;
        #pragma unroll
        for (int lh = 0; lh < 2; ++lh)
            #pragma unroll
            for (int ks = 0; ks < 4; ++ks) {
                a1re[lh][ks] = *(const half8*)(rb + lh * 2048 + ks * 512 + lane * 8);
                a1im[lh][ks] = *(const half8*)(rb + 4096 + lh * 2048 + ks * 512 + lane * 8);
            }
    }

    f32x16 accRe[2], accIm[2];
    #pragma unroll
    for (int mt = 0; mt < 2; ++mt)
        #pragma unroll
        for (int i = 0; i < 16; ++i) { accRe[mt][i] = 0.f; accIm[mt][i] = 0.f; }

    if (IT == 0) run_layer<0>(kraus, a1re, a1im, accRe, accIm, lane);
    else         run_layer<1>(kraus, a1re, a1im, accRe, accIm, lane);

    // ---- epilogue: acc lane=col m_rel, reg 4g+j -> row i = 32*IT + 8g + 4hl + j ----
    if (!last) {
        // write rho_new^T in fragment order: row=m=32mt+l31, col=i
        _Float16* ob = rho_out + (size_t)b * 2 * D * D;
        #pragma unroll
        for (int mt = 0; mt < 2; ++mt) {
            #pragma unroll
            for (int g = 0; g < 4; ++g) {
                Pack4 pr, pi;
                #pragma unroll
                for (int j = 0; j < 4; ++j) {
                    pr.h[j] = (_Float16)accRe[mt][4 * g + j];
                    pi.h[j] = (_Float16)accIm[mt][4 * g + j];
                }
                const int off = mt * 2048 + (4 * IT + g) * 256 + l31 * 8 + 4 * hl;
                *(uint2*)(ob + off)        = pr.u;
                *(uint2*)(ob + 4096 + off) = pi.u;
            }
        }
    } else {
        float* o0 = final_out + (size_t)b * 4096;            // [0][b][i][m]
        float* o1 = final_out + (size_t)(NB + b) * 4096;     // [1][b][i][m]
        #pragma unroll
        for (int mt = 0; mt < 2; ++mt) {
            const int m = 32 * mt + l31;
            #pragma unroll
            for (int g = 0; g < 4; ++g) {
                #pragma unroll
                for (int j = 0; j < 4; ++j) {
                    const int i = 32 * IT + 8 * g + 4 * hl + j;
                    o0[i * D + m] = accRe[mt][4 * g + j];
                    o1[i * D + m] = accIm[mt][4 * g + j];
                }
            }
        }
    }
}

extern "C" void kernel_launch(void* const* d_in, const int* in_sizes, int n_in,
                              void* d_out, int out_size, void* d_ws, size_t ws_size,
                              hipStream_t stream) {
    const float* state_re = (const float*)d_in[0];
    const float* state_im = (const float*)d_in[1];
    const float* kraus_re = (const float*)d_in[2];
    const float* kraus_im = (const float*)d_in[3];

    _Float16* kraus_h = (_Float16*)d_ws;                         // 2 MB in ws (frag order)
    // ping-pong rho buffers live inside d_out (2 x 16 MB = out_size exactly).
    _Float16* bufA = (_Float16*)d_out;
    _Float16* bufB = (_Float16*)((char*)d_out + (size_t)NB * 2 * D * D * sizeof(_Float16));
    float* fout = (float*)d_out;

    kconv_kernel<<<dim3(512, 2), 256, 0, stream>>>(kraus_re, kraus_im, kraus_h);
    sconv_kernel<<<NB, 256, 0, stream>>>(state_re, state_im, bufA);

    for (int l = 0; l < NL; ++l) {
        const _Float16* in = (l & 1) ? bufB : bufA;
        _Float16* out      = (l & 1) ? bufA : bufB;
        layer_kernel<<<dim3(NB, 2), 64, 0, stream>>>(in, out, fout,
                                                     kraus_h + (size_t)l * NKR * 2 * D * D,
                                                     (l == NL - 1) ? 1 : 0);
    }
}

// Round 9
// 589.028 us; speedup vs baseline: 4.3713x; 1.1680x over previous
//
#include <hip/hip_runtime.h>
#include <hip/hip_fp16.h>

#define D 64
#define NKR 16
#define NB 1024
#define NL 8

typedef __attribute__((ext_vector_type(8))) _Float16 half8;
typedef __attribute__((ext_vector_type(16))) float f32x16;
typedef __attribute__((ext_vector_type(4))) int i32x4;

static __device__ __forceinline__ half8 neg8(half8 x) {
    i32x4 u = __builtin_bit_cast(i32x4, x);
    u = u ^ (int)0x80008000;
    return __builtin_bit_cast(half8, u);
}

static __device__ __forceinline__ unsigned pkrtz(float a, float b) {
    auto h = __builtin_amdgcn_cvt_pkrtz(a, b);   // __fp16 ext_vector_type(2)
    return __builtin_bit_cast(unsigned, h);
}

// v_permlane32_swap_b32: a.row1 <-> b.row0 (row = 32-lane half).
static __device__ __forceinline__ void plswap(unsigned &a, unsigned &b) {
    asm volatile("v_permlane32_swap_b32 %0, %1" : "+v"(a), "+v"(b));
}

union Pack4 { _Float16 h[4]; uint2 u; };
union H8 { unsigned u[4]; uint2 v[2]; half8 h; };

#define MFMA __builtin_amdgcn_mfma_f32_32x32x16_f16

// ---------------------------------------------------------------------------
// Fragment-order layout for 64x64 f16 matrices (both kraus and rho^T):
//   element (row, col) -> ihalf*2048 + (2*(col>>4) + ((col>>3)&1))*256 + (row&31)*8 + (col&7)
//   with ihalf = row>>5.  A wave's MFMA fragment (ks) for half ih is then ONE fully
//   coalesced 16B/lane load at: base + ih*2048 + ks*512 + lane*8   (halves).
// ---------------------------------------------------------------------------

// kraus fp32 -> fp16 fragment order: [L*K][plane][ihalf][slot][l31][8]
__global__ void kconv_kernel(const float* __restrict__ re, const float* __restrict__ im,
                             _Float16* __restrict__ out) {
    int plane = blockIdx.y;
    int idx = blockIdx.x * blockDim.x + threadIdx.x;
    const float* src = plane ? im : re;
    float4 v = ((const float4*)src)[idx];
    int e = idx * 4;
    int lk = e >> 12;
    int rem = e & 4095;
    int row = rem >> 6, col = rem & 63;          // col multiple of 4
    int ihalf = row >> 5, r31 = row & 31;
    int ks = col >> 4, hl2 = (col >> 3) & 1, c = col & 7;   // c in {0,4}
    Pack4 p;
    p.h[0] = (_Float16)v.x; p.h[1] = (_Float16)v.y;
    p.h[2] = (_Float16)v.z; p.h[3] = (_Float16)v.w;
    size_t off = (size_t)(lk * 2 + plane) * 4096 + ihalf * 2048
               + (2 * ks + hl2) * 256 + r31 * 8 + c;
    *(uint2*)(out + off) = p.u;
}

// state fp32 -> fp16, rho^T in fragment order: out[b][plane][fragment-layout of rho^T]
__global__ void sconv_kernel(const float* __restrict__ re, const float* __restrict__ im,
                             _Float16* __restrict__ out) {
    __shared__ float tile[64][65];
    int b = blockIdx.x;
    int t = threadIdx.x;
    for (int plane = 0; plane < 2; ++plane) {
        const float* src = (plane ? im : re) + (size_t)b * 4096;
        __syncthreads();
        #pragma unroll
        for (int i = 0; i < 16; ++i) {
            int e = t + 256 * i;
            tile[e >> 6][e & 63] = src[e];          // tile[i][j] = state[i][j]
        }
        __syncthreads();
        _Float16* o = out + ((size_t)b * 2 + plane) * 4096;
        #pragma unroll
        for (int i = 0; i < 16; ++i) {
            int oi = t + 256 * i;
            int lh = oi >> 11, slot = (oi >> 8) & 7, r = (oi >> 3) & 31, c = oi & 7;
            int col = 16 * (slot >> 1) + 8 * (slot & 1) + c;
            int row = 32 * lh + r;
            o[oi] = (_Float16)tile[col][row];       // rho^T[row][col] = state[col][row]
        }
    }
}

// Stage-1 f32x16 tile (lane=col i, reg 4g+j -> row l_rel=8g+4hl+j) -> two stage-2
// A-fragments (lane=row i, halves l_rel 16c+8hl+0..7) in registers: 8 cvt + 4 permlane.
static __device__ __forceinline__ void exchange(const f32x16 &dd, half8 &f0, half8 &f1) {
    unsigned A0 = pkrtz(dd[0],  dd[1]),  B0 = pkrtz(dd[2],  dd[3]);
    unsigned A1 = pkrtz(dd[4],  dd[5]),  B1 = pkrtz(dd[6],  dd[7]);
    unsigned A2 = pkrtz(dd[8],  dd[9]),  B2 = pkrtz(dd[10], dd[11]);
    unsigned A3 = pkrtz(dd[12], dd[13]), B3 = pkrtz(dd[14], dd[15]);
    plswap(A0, A1);
    plswap(B0, B1);
    plswap(A2, A3);
    plswap(B2, B3);
    H8 h0; h0.u[0] = A0; h0.u[1] = B0; h0.u[2] = A1; h0.u[3] = B1; f0 = h0.h;
    H8 h1; h1.u[0] = A2; h1.u[1] = B2; h1.u[2] = A3; h1.u[3] = B3; f1 = h1.h;
}

// One kraus step. Fused stage-1: both lh tiles computed concurrently (4 independent
// MFMA chains: dre0,dim0,dre1,dim1, round-robin issue); a1 fragments streamed from
// L1/L2 one ks ahead (4 half8 live, not 16). One exchange point per kstep. Fused
// stage-2: 32 MFMAs in 4 acc chains. 32 coalesced loads, no LDS, no barriers.
template<int IT>
static __device__ __forceinline__ void kstep(
    const _Float16* __restrict__ kb,     // this k: [plane][ihalf][slot][l31][8]
    const _Float16* __restrict__ rb,     // this rho: fragment-order rho^T
    f32x16 (&accRe)[2], f32x16 (&accIm)[2],
    int lane)
{
    const _Float16* bo = kb + IT * 2048;          // own half (stage1 B + stage2 mt=IT)
    const _Float16* bx = kb + (1 - IT) * 2048;    // other half (stage2 mt=1-IT)

    half8 bre[4], bim[4];
    #pragma unroll
    for (int ks = 0; ks < 4; ++ks) {
        bre[ks] = *(const half8*)(bo + ks * 512 + lane * 8);
        bim[ks] = *(const half8*)(bo + 4096 + ks * 512 + lane * 8);
    }

    // ---- fused stage 1: 4 chains, a1 streamed one ks ahead ----
    half8 ar0 = *(const half8*)(rb + lane * 8);
    half8 ai0 = *(const half8*)(rb + 4096 + lane * 8);
    half8 ar1 = *(const half8*)(rb + 2048 + lane * 8);
    half8 ai1 = *(const half8*)(rb + 6144 + lane * 8);

    f32x16 dre0, dim0, dre1, dim1;
    #pragma unroll
    for (int i = 0; i < 16; ++i) { dre0[i] = 0.f; dim0[i] = 0.f; dre1[i] = 0.f; dim1[i] = 0.f; }

    __builtin_amdgcn_s_setprio(1);
    #pragma unroll
    for (int ks = 0; ks < 4; ++ks) {
        half8 xr0, xi0, xr1, xi1;
        if (ks < 3) {
            xr0 = *(const half8*)(rb + (ks + 1) * 512 + lane * 8);
            xi0 = *(const half8*)(rb + 4096 + (ks + 1) * 512 + lane * 8);
            xr1 = *(const half8*)(rb + 2048 + (ks + 1) * 512 + lane * 8);
            xi1 = *(const half8*)(rb + 6144 + (ks + 1) * 512 + lane * 8);
        }
        half8 bn = neg8(bim[ks]);
        dre0 = MFMA(ar0, bre[ks], dre0, 0, 0, 0);
        dre1 = MFMA(ar1, bre[ks], dre1, 0, 0, 0);
        dim0 = MFMA(ar0, bim[ks], dim0, 0, 0, 0);
        dim1 = MFMA(ar1, bim[ks], dim1, 0, 0, 0);
        dre0 = MFMA(ai0, bn, dre0, 0, 0, 0);
        dre1 = MFMA(ai1, bn, dre1, 0, 0, 0);
        dim0 = MFMA(ai0, bre[ks], dim0, 0, 0, 0);
        dim1 = MFMA(ai1, bre[ks], dim1, 0, 0, 0);
        if (ks < 3) { ar0 = xr0; ai0 = xi0; ar1 = xr1; ai1 = xi1; }
    }
    __builtin_amdgcn_s_setprio(0);

    // ---- other-half B loads: issued before exchange, covered by its VALU ----
    half8 br2[4], bi2[4];
    #pragma unroll
    for (int ks = 0; ks < 4; ++ks) {
        br2[ks] = *(const half8*)(bx + ks * 512 + lane * 8);
        bi2[ks] = *(const half8*)(bx + 4096 + ks * 512 + lane * 8);
    }

    // ---- single exchange point: af[ks] pairs with b[ks] in stage 2 ----
    half8 afr[4], afi[4];
    exchange(dre0, afr[0], afr[1]);
    exchange(dre1, afr[2], afr[3]);
    exchange(dim0, afi[0], afi[1]);
    exchange(dim1, afi[2], afi[3]);

    // ---- fused stage 2: 4 acc chains, round-robin ----
    __builtin_amdgcn_s_setprio(1);
    #pragma unroll
    for (int ks = 0; ks < 4; ++ks) {
        half8 an = neg8(afr[ks]);
        accRe[IT]     = MFMA(afr[ks], bre[ks], accRe[IT],     0, 0, 0);
        accIm[IT]     = MFMA(afi[ks], bre[ks], accIm[IT],     0, 0, 0);
        accRe[1 - IT] = MFMA(afr[ks], br2[ks], accRe[1 - IT], 0, 0, 0);
        accIm[1 - IT] = MFMA(afi[ks], br2[ks], accIm[1 - IT], 0, 0, 0);
        accRe[IT]     = MFMA(afi[ks], bim[ks], accRe[IT],     0, 0, 0);
        accIm[IT]     = MFMA(an,      bim[ks], accIm[IT],     0, 0, 0);  // Im -= Tre*Kim
        accRe[1 - IT] = MFMA(afi[ks], bi2[ks], accRe[1 - IT], 0, 0, 0);
        accIm[1 - IT] = MFMA(an,      bi2[ks], accIm[1 - IT], 0, 0, 0);
    }
    __builtin_amdgcn_s_setprio(0);
}

template<int IT>
static __device__ __forceinline__ void run_layer(
    const _Float16* __restrict__ kraus,
    const _Float16* __restrict__ rb,
    f32x16 (&accRe)[2], f32x16 (&accIm)[2],
    int lane)
{
    #pragma unroll 1
    for (int k = 0; k < NKR; ++k)
        kstep<IT>(kraus + (size_t)k * 8192, rb, accRe, accIm, lane);
}

// One wave per block; grid (NB, 2): blockIdx.x = rho, blockIdx.y = output i-tile.
// No LDS, no barriers: 2048 free-running waves, K fragments read coalesced from L1/L2.
__global__ __launch_bounds__(64, 2) void layer_kernel(
    const _Float16* __restrict__ rho_in,    // fragment-order rho^T, [b][plane][4096]
    _Float16* __restrict__ rho_out,
    float* __restrict__ final_out,
    const _Float16* __restrict__ kraus,     // this layer, fragment order: [K][plane][4096]
    int last)
{
    const int b    = blockIdx.x;
    const int IT   = blockIdx.y;
    const int lane = threadIdx.x;
    const int l31  = lane & 31;
    const int hl   = lane >> 5;

    const _Float16* rb = rho_in + (size_t)b * 2 * D * D;

    f32x16 accRe[2], accIm[2];
    #pragma unroll
    for (int mt = 0; mt < 2; ++mt)
        #pragma unroll
        for (int i = 0; i < 16; ++i) { accRe[mt][i] = 0.f; accIm[mt][i] = 0.f; }

    if (IT == 0) run_layer<0>(kraus, rb, accRe, accIm, lane);
    else         run_layer<1>(kraus, rb, accRe, accIm, lane);

    // ---- epilogue: acc lane=col m_rel, reg 4g+j -> row i = 32*IT + 8g + 4hl + j ----
    if (!last) {
        // write rho_new^T in fragment order: row=m=32mt+l31, col=i
        _Float16* ob = rho_out + (size_t)b * 2 * D * D;
        #pragma unroll
        for (int mt = 0; mt < 2; ++mt) {
            #pragma unroll
            for (int g = 0; g < 4; ++g) {
                Pack4 pr, pi;
                #pragma unroll
                for (int j = 0; j < 4; ++j) {
                    pr.h[j] = (_Float16)accRe[mt][4 * g + j];
                    pi.h[j] = (_Float16)accIm[mt][4 * g + j];
                }
                const int off = mt * 2048 + (4 * IT + g) * 256 + l31 * 8 + 4 * hl;
                *(uint2*)(ob + off)        = pr.u;
                *(uint2*)(ob + 4096 + off) = pi.u;
            }
        }
    } else {
        float* o0 = final_out + (size_t)b * 4096;            // [0][b][i][m]
        float* o1 = final_out + (size_t)(NB + b) * 4096;     // [1][b][i][m]
        #pragma unroll
        for (int mt = 0; mt < 2; ++mt) {
            const int m = 32 * mt + l31;
            #pragma unroll
            for (int g = 0; g < 4; ++g) {
                #pragma unroll
                for (int j = 0; j < 4; ++j) {
                    const int i = 32 * IT + 8 * g + 4 * hl + j;
                    o0[i * D + m] = accRe[mt][4 * g + j];
                    o1[i * D + m] = accIm[mt][4 * g + j];
                }
            }
        }
    }
}

extern "C" void kernel_launch(void* const* d_in, const int* in_sizes, int n_in,
                              void* d_out, int out_size, void* d_ws, size_t ws_size,
                              hipStream_t stream) {
    const float* state_re = (const float*)d_in[0];
    const float* state_im = (const float*)d_in[1];
    const float* kraus_re = (const float*)d_in[2];
    const float* kraus_im = (const float*)d_in[3];

    _Float16* kraus_h = (_Float16*)d_ws;                         // 2 MB in ws (frag order)
    // ping-pong rho buffers live inside d_out (2 x 16 MB = out_size exactly).
    _Float16* bufA = (_Float16*)d_out;
    _Float16* bufB = (_Float16*)((char*)d_out + (size_t)NB * 2 * D * D * sizeof(_Float16));
    float* fout = (float*)d_out;

    kconv_kernel<<<dim3(512, 2), 256, 0, stream>>>(kraus_re, kraus_im, kraus_h);
    sconv_kernel<<<NB, 256, 0, stream>>>(state_re, state_im, bufA);

    for (int l = 0; l < NL; ++l) {
        const _Float16* in = (l & 1) ? bufB : bufA;
        _Float16* out      = (l & 1) ? bufA : bufB;
        layer_kernel<<<dim3(NB, 2), 64, 0, stream>>>(in, out, fout,
                                                     kraus_h + (size_t)l * NKR * 2 * D * D,
                                                     (l == NL - 1) ? 1 : 0);
    }
}

// Round 10
// 554.549 us; speedup vs baseline: 4.6431x; 1.0622x over previous
//
#include <hip/hip_runtime.h>
#include <hip/hip_fp16.h>

#define D 64
#define NKR 16
#define NB 1024
#define NL 8

typedef __attribute__((ext_vector_type(8))) _Float16 half8;
typedef __attribute__((ext_vector_type(16))) float f32x16;
typedef __attribute__((ext_vector_type(4))) int i32x4;

static __device__ __forceinline__ half8 neg8(half8 x) {
    i32x4 u = __builtin_bit_cast(i32x4, x);
    u = u ^ (int)0x80008000;
    return __builtin_bit_cast(half8, u);
}

static __device__ __forceinline__ unsigned pkrtz(float a, float b) {
    auto h = __builtin_amdgcn_cvt_pkrtz(a, b);   // __fp16 ext_vector_type(2)
    return __builtin_bit_cast(unsigned, h);
}

// v_permlane32_swap_b32: a.row1 <-> b.row0 (row = 32-lane half).
static __device__ __forceinline__ void plswap(unsigned &a, unsigned &b) {
    asm volatile("v_permlane32_swap_b32 %0, %1" : "+v"(a), "+v"(b));
}

union Pack4 { _Float16 h[4]; uint2 u; };
union H8 { unsigned u[4]; uint2 v[2]; half8 h; };

#define GLDS16(gp, lp) \
    __builtin_amdgcn_global_load_lds((const __attribute__((address_space(1))) void*)(gp), \
                                     (__attribute__((address_space(3))) void*)(lp), 16, 0, 0)

#define MFMA __builtin_amdgcn_mfma_f32_32x32x16_f16

// ---------------------------------------------------------------------------
// Fragment-order layout for 64x64 f16 matrices (both kraus and rho^T):
//   element (row, col) -> ihalf*2048 + (2*(col>>4) + ((col>>3)&1))*256 + (row&31)*8 + (col&7)
//   with ihalf = row>>5.  A wave's MFMA fragment (ks) for half ih is then ONE fully
//   coalesced 16B/lane load at: base + ih*2048 + ks*512 + lane*8   (halves).
// ---------------------------------------------------------------------------

// kraus fp32 -> fp16 fragment order: [L*K][plane][ihalf][slot][l31][8]
__global__ void kconv_kernel(const float* __restrict__ re, const float* __restrict__ im,
                             _Float16* __restrict__ out) {
    int plane = blockIdx.y;
    int idx = blockIdx.x * blockDim.x + threadIdx.x;
    const float* src = plane ? im : re;
    float4 v = ((const float4*)src)[idx];
    int e = idx * 4;
    int lk = e >> 12;
    int rem = e & 4095;
    int row = rem >> 6, col = rem & 63;          // col multiple of 4
    int ihalf = row >> 5, r31 = row & 31;
    int ks = col >> 4, hl2 = (col >> 3) & 1, c = col & 7;   // c in {0,4}
    Pack4 p;
    p.h[0] = (_Float16)v.x; p.h[1] = (_Float16)v.y;
    p.h[2] = (_Float16)v.z; p.h[3] = (_Float16)v.w;
    size_t off = (size_t)(lk * 2 + plane) * 4096 + ihalf * 2048
               + (2 * ks + hl2) * 256 + r31 * 8 + c;
    *(uint2*)(out + off) = p.u;
}

// state fp32 -> fp16, rho^T in fragment order: out[b][plane][fragment-layout of rho^T]
__global__ void sconv_kernel(const float* __restrict__ re, const float* __restrict__ im,
                             _Float16* __restrict__ out) {
    __shared__ float tile[64][65];
    int b = blockIdx.x;
    int t = threadIdx.x;
    for (int plane = 0; plane < 2; ++plane) {
        const float* src = (plane ? im : re) + (size_t)b * 4096;
        __syncthreads();
        #pragma unroll
        for (int i = 0; i < 16; ++i) {
            int e = t + 256 * i;
            tile[e >> 6][e & 63] = src[e];          // tile[i][j] = state[i][j]
        }
        __syncthreads();
        _Float16* o = out + ((size_t)b * 2 + plane) * 4096;
        #pragma unroll
        for (int i = 0; i < 16; ++i) {
            int oi = t + 256 * i;
            int lh = oi >> 11, slot = (oi >> 8) & 7, r = (oi >> 3) & 31, c = oi & 7;
            int col = 16 * (slot >> 1) + 8 * (slot & 1) + c;
            int row = 32 * lh + r;
            o[oi] = (_Float16)tile[col][row];       // rho^T[row][col] = state[col][row]
        }
    }
}

// Stage-1 f32x16 tile (lane=col i, reg 4g+j -> row l_rel=8g+4hl+j) -> two stage-2
// A-fragments (lane=row i, halves l_rel 16c+8hl+0..7) in registers: 8 cvt + 4 permlane.
static __device__ __forceinline__ void exchange(const f32x16 &dd, half8 &f0, half8 &f1) {
    unsigned A0 = pkrtz(dd[0],  dd[1]),  B0 = pkrtz(dd[2],  dd[3]);
    unsigned A1 = pkrtz(dd[4],  dd[5]),  B1 = pkrtz(dd[6],  dd[7]);
    unsigned A2 = pkrtz(dd[8],  dd[9]),  B2 = pkrtz(dd[10], dd[11]);
    unsigned A3 = pkrtz(dd[12], dd[13]), B3 = pkrtz(dd[14], dd[15]);
    plswap(A0, A1);
    plswap(B0, B1);
    plswap(A2, A3);
    plswap(B2, B3);
    H8 h0; h0.u[0] = A0; h0.u[1] = B0; h0.u[2] = A1; h0.u[3] = B1; f0 = h0.h;
    H8 h1; h1.u[0] = A2; h1.u[1] = B2; h1.u[2] = A3; h1.u[3] = B3; f1 = h1.h;
}

// One kraus step. Stage 1 fused across both lh: 32 MFMAs in 4 independent chains
// (dre0,dre1,dim0,dim1 round-robin) so dependent-MFMA latency never gates issue.
// a1 fragments come from block-shared LDS (read fresh each kstep, 64 transient regs,
// no persistent a1). One exchange point; stage 2 = 32 MFMAs in 4 acc chains.
template<int IT>
static __device__ __forceinline__ void kstep(
    const _Float16* __restrict__ kb,     // this k: [plane][ihalf][slot][l31][8]
    const _Float16* __restrict__ rl,     // LDS rho^T, fragment order (8192 halves)
    f32x16 (&accRe)[2], f32x16 (&accIm)[2],
    int lane)
{
    const _Float16* bo = kb + IT * 2048;          // own half (stage1 B + stage2 mt=IT)
    const _Float16* bx = kb + (1 - IT) * 2048;    // other half (stage2 mt=1-IT)

    half8 bre[4], bim[4];
    #pragma unroll
    for (int ks = 0; ks < 4; ++ks) {
        bre[ks] = *(const half8*)(bo + ks * 512 + lane * 8);
        bim[ks] = *(const half8*)(bo + 4096 + ks * 512 + lane * 8);
    }

    // a1 fragments from LDS (ds_read_b128, conflict-free linear layout)
    half8 ar0[4], ai0[4], ar1[4], ai1[4];
    #pragma unroll
    for (int ks = 0; ks < 4; ++ks) {
        ar0[ks] = *(const half8*)(rl + ks * 512 + lane * 8);
        ai0[ks] = *(const half8*)(rl + 4096 + ks * 512 + lane * 8);
        ar1[ks] = *(const half8*)(rl + 2048 + ks * 512 + lane * 8);
        ai1[ks] = *(const half8*)(rl + 6144 + ks * 512 + lane * 8);
    }

    f32x16 dre0, dim0, dre1, dim1;
    #pragma unroll
    for (int i = 0; i < 16; ++i) { dre0[i] = 0.f; dim0[i] = 0.f; dre1[i] = 0.f; dim1[i] = 0.f; }

    __builtin_amdgcn_s_setprio(1);
    #pragma unroll
    for (int ks = 0; ks < 4; ++ks) {
        half8 bn = neg8(bim[ks]);
        dre0 = MFMA(ar0[ks], bre[ks], dre0, 0, 0, 0);
        dre1 = MFMA(ar1[ks], bre[ks], dre1, 0, 0, 0);
        dim0 = MFMA(ar0[ks], bim[ks], dim0, 0, 0, 0);
        dim1 = MFMA(ar1[ks], bim[ks], dim1, 0, 0, 0);
        dre0 = MFMA(ai0[ks], bn, dre0, 0, 0, 0);
        dre1 = MFMA(ai1[ks], bn, dre1, 0, 0, 0);
        dim0 = MFMA(ai0[ks], bre[ks], dim0, 0, 0, 0);
        dim1 = MFMA(ai1[ks], bre[ks], dim1, 0, 0, 0);
    }
    __builtin_amdgcn_s_setprio(0);

    // other-half B loads: issued before exchange, covered by its VALU
    half8 br2[4], bi2[4];
    #pragma unroll
    for (int ks = 0; ks < 4; ++ks) {
        br2[ks] = *(const half8*)(bx + ks * 512 + lane * 8);
        bi2[ks] = *(const half8*)(bx + 4096 + ks * 512 + lane * 8);
    }

    // single exchange point: af[ks] pairs with b[ks] in stage 2
    half8 afr[4], afi[4];
    exchange(dre0, afr[0], afr[1]);
    exchange(dre1, afr[2], afr[3]);
    exchange(dim0, afi[0], afi[1]);
    exchange(dim1, afi[2], afi[3]);

    // fused stage 2: 4 acc chains, round-robin
    __builtin_amdgcn_s_setprio(1);
    #pragma unroll
    for (int ks = 0; ks < 4; ++ks) {
        half8 an = neg8(afr[ks]);
        accRe[IT]     = MFMA(afr[ks], bre[ks], accRe[IT],     0, 0, 0);
        accIm[IT]     = MFMA(afi[ks], bre[ks], accIm[IT],     0, 0, 0);
        accRe[1 - IT] = MFMA(afr[ks], br2[ks], accRe[1 - IT], 0, 0, 0);
        accIm[1 - IT] = MFMA(afi[ks], br2[ks], accIm[1 - IT], 0, 0, 0);
        accRe[IT]     = MFMA(afi[ks], bim[ks], accRe[IT],     0, 0, 0);
        accIm[IT]     = MFMA(an,      bim[ks], accIm[IT],     0, 0, 0);  // Im -= Tre*Kim
        accRe[1 - IT] = MFMA(afi[ks], bi2[ks], accRe[1 - IT], 0, 0, 0);
        accIm[1 - IT] = MFMA(an,      bi2[ks], accIm[1 - IT], 0, 0, 0);
    }
    __builtin_amdgcn_s_setprio(0);
}

template<int IT>
static __device__ __forceinline__ void run_layer(
    const _Float16* __restrict__ kraus,
    const _Float16* __restrict__ rl,
    f32x16 (&accRe)[2], f32x16 (&accIm)[2],
    int lane)
{
    #pragma unroll 1
    for (int k = 0; k < NKR; ++k)
        kstep<IT>(kraus + (size_t)k * 8192, rl, accRe, accIm, lane);
}

// One block per rho, 128 threads = 2 waves (IT = wave id). rho^T staged once into
// 16 KB LDS (shared by both waves, read-only after one barrier); waves then free-run.
// 4 blocks/CU. No per-kstep barriers.
__global__ __launch_bounds__(128, 2) void layer_kernel(
    const _Float16* __restrict__ rho_in,    // fragment-order rho^T, [b][plane][4096]
    _Float16* __restrict__ rho_out,
    float* __restrict__ final_out,
    const _Float16* __restrict__ kraus,     // this layer, fragment order: [K][plane][4096]
    int last)
{
    __shared__ __align__(16) _Float16 Rlds[2 * D * D];   // 16 KB

    const int b    = blockIdx.x;
    const int t    = threadIdx.x;
    const int IT   = t >> 6;
    const int lane = t & 63;
    const int l31  = lane & 31;
    const int hl   = lane >> 5;

    // ---- stage rho^T into LDS (linear copy; wave wv fills its 8 KB half) ----
    {
        const char* rb = (const char*)(rho_in + (size_t)b * 2 * D * D);
        const int off = IT * 8192;
        #pragma unroll
        for (int r = 0; r < 8; ++r)
            GLDS16(rb + off + r * 1024 + lane * 16, (char*)Rlds + off + r * 1024);
    }

    f32x16 accRe[2], accIm[2];
    #pragma unroll
    for (int mt = 0; mt < 2; ++mt)
        #pragma unroll
        for (int i = 0; i < 16; ++i) { accRe[mt][i] = 0.f; accIm[mt][i] = 0.f; }

    __syncthreads();   // Rlds ready (vmcnt drained by barrier); waves free-run after

    if (IT == 0) run_layer<0>(kraus, Rlds, accRe, accIm, lane);
    else         run_layer<1>(kraus, Rlds, accRe, accIm, lane);

    // ---- epilogue: acc lane=col m_rel, reg 4g+j -> row i = 32*IT + 8g + 4hl + j ----
    if (!last) {
        // write rho_new^T in fragment order: row=m=32mt+l31, col=i
        _Float16* ob = rho_out + (size_t)b * 2 * D * D;
        #pragma unroll
        for (int mt = 0; mt < 2; ++mt) {
            #pragma unroll
            for (int g = 0; g < 4; ++g) {
                Pack4 pr, pi;
                #pragma unroll
                for (int j = 0; j < 4; ++j) {
                    pr.h[j] = (_Float16)accRe[mt][4 * g + j];
                    pi.h[j] = (_Float16)accIm[mt][4 * g + j];
                }
                const int off = mt * 2048 + (4 * IT + g) * 256 + l31 * 8 + 4 * hl;
                *(uint2*)(ob + off)        = pr.u;
                *(uint2*)(ob + 4096 + off) = pi.u;
            }
        }
    } else {
        float* o0 = final_out + (size_t)b * 4096;            // [0][b][i][m]
        float* o1 = final_out + (size_t)(NB + b) * 4096;     // [1][b][i][m]
        #pragma unroll
        for (int mt = 0; mt < 2; ++mt) {
            const int m = 32 * mt + l31;
            #pragma unroll
            for (int g = 0; g < 4; ++g) {
                #pragma unroll
                for (int j = 0; j < 4; ++j) {
                    const int i = 32 * IT + 8 * g + 4 * hl + j;
                    o0[i * D + m] = accRe[mt][4 * g + j];
                    o1[i * D + m] = accIm[mt][4 * g + j];
                }
            }
        }
    }
}

extern "C" void kernel_launch(void* const* d_in, const int* in_sizes, int n_in,
                              void* d_out, int out_size, void* d_ws, size_t ws_size,
                              hipStream_t stream) {
    const float* state_re = (const float*)d_in[0];
    const float* state_im = (const float*)d_in[1];
    const float* kraus_re = (const float*)d_in[2];
    const float* kraus_im = (const float*)d_in[3];

    _Float16* kraus_h = (_Float16*)d_ws;                         // 2 MB in ws (frag order)
    // ping-pong rho buffers live inside d_out (2 x 16 MB = out_size exactly).
    _Float16* bufA = (_Float16*)d_out;
    _Float16* bufB = (_Float16*)((char*)d_out + (size_t)NB * 2 * D * D * sizeof(_Float16));
    float* fout = (float*)d_out;

    kconv_kernel<<<dim3(512, 2), 256, 0, stream>>>(kraus_re, kraus_im, kraus_h);
    sconv_kernel<<<NB, 256, 0, stream>>>(state_re, state_im, bufA);

    for (int l = 0; l < NL; ++l) {
        const _Float16* in = (l & 1) ? bufB : bufA;
        _Float16* out      = (l & 1) ? bufA : bufB;
        layer_kernel<<<NB, 128, 0, stream>>>(in, out, fout,
                                             kraus_h + (size_t)l * NKR * 2 * D * D,
                                             (l == NL - 1) ? 1 : 0);
    }
}

// Round 12
// 517.374 us; speedup vs baseline: 4.9767x; 1.0719x over previous
//
#include <hip/hip_runtime.h>
#include <hip/hip_fp16.h>

#define D 64
#define NKR 16
#define NB 1024
#define NL 8

typedef __attribute__((ext_vector_type(8))) _Float16 half8;
typedef __attribute__((ext_vector_type(16))) float f32x16;
typedef __attribute__((ext_vector_type(4))) int i32x4;

static __device__ __forceinline__ half8 neg8(half8 x) {
    i32x4 u = __builtin_bit_cast(i32x4, x);
    u = u ^ (int)0x80008000;
    return __builtin_bit_cast(half8, u);
}

static __device__ __forceinline__ unsigned pkrtz(float a, float b) {
    auto h = __builtin_amdgcn_cvt_pkrtz(a, b);   // __fp16 ext_vector_type(2)
    return __builtin_bit_cast(unsigned, h);
}

// v_permlane32_swap_b32: a.row1 <-> b.row0 (row = 32-lane half).
static __device__ __forceinline__ void plswap(unsigned &a, unsigned &b) {
    asm volatile("v_permlane32_swap_b32 %0, %1" : "+v"(a), "+v"(b));
}

union Pack4 { _Float16 h[4]; uint2 u; };
union H8 { unsigned u[4]; uint2 v[2]; half8 h; };

#define GLDS16(gp, lp) \
    __builtin_amdgcn_global_load_lds((const __attribute__((address_space(1))) void*)(gp), \
                                     (__attribute__((address_space(3))) void*)(lp), 16, 0, 0)

#define MFMA __builtin_amdgcn_mfma_f32_32x32x16_f16

// ---------------------------------------------------------------------------
// Fragment-order layout for 64x64 f16 matrices (both kraus and rho^T):
//   element (row, col) -> ihalf*2048 + (2*(col>>4) + ((col>>3)&1))*256 + (row&31)*8 + (col&7)
//   with ihalf = row>>5.  A wave's MFMA fragment (ks) for half ih is then ONE fully
//   coalesced 16B/lane load at: base + ih*2048 + ks*512 + lane*8   (halves).
// ---------------------------------------------------------------------------

// kraus fp32 -> fp16 fragment order: [L*K][plane][ihalf][slot][l31][8]
__global__ void kconv_kernel(const float* __restrict__ re, const float* __restrict__ im,
                             _Float16* __restrict__ out) {
    int plane = blockIdx.y;
    int idx = blockIdx.x * blockDim.x + threadIdx.x;
    const float* src = plane ? im : re;
    float4 v = ((const float4*)src)[idx];
    int e = idx * 4;
    int lk = e >> 12;
    int rem = e & 4095;
    int row = rem >> 6, col = rem & 63;          // col multiple of 4
    int ihalf = row >> 5, r31 = row & 31;
    int ks = col >> 4, hl2 = (col >> 3) & 1, c = col & 7;   // c in {0,4}
    Pack4 p;
    p.h[0] = (_Float16)v.x; p.h[1] = (_Float16)v.y;
    p.h[2] = (_Float16)v.z; p.h[3] = (_Float16)v.w;
    size_t off = (size_t)(lk * 2 + plane) * 4096 + ihalf * 2048
               + (2 * ks + hl2) * 256 + r31 * 8 + c;
    *(uint2*)(out + off) = p.u;
}

// state fp32 -> fp16, rho^T in fragment order: out[b][plane][fragment-layout of rho^T]
__global__ void sconv_kernel(const float* __restrict__ re, const float* __restrict__ im,
                             _Float16* __restrict__ out) {
    __shared__ float tile[64][65];
    int b = blockIdx.x;
    int t = threadIdx.x;
    for (int plane = 0; plane < 2; ++plane) {
        const float* src = (plane ? im : re) + (size_t)b * 4096;
        __syncthreads();
        #pragma unroll
        for (int i = 0; i < 16; ++i) {
            int e = t + 256 * i;
            tile[e >> 6][e & 63] = src[e];          // tile[i][j] = state[i][j]
        }
        __syncthreads();
        _Float16* o = out + ((size_t)b * 2 + plane) * 4096;
        #pragma unroll
        for (int i = 0; i < 16; ++i) {
            int oi = t + 256 * i;
            int lh = oi >> 11, slot = (oi >> 8) & 7, r = (oi >> 3) & 31, c = oi & 7;
            int col = 16 * (slot >> 1) + 8 * (slot & 1) + c;
            int row = 32 * lh + r;
            o[oi] = (_Float16)tile[col][row];       // rho^T[row][col] = state[col][row]
        }
    }
}

// Stage-1 f32x16 tile (lane=col i, reg 4g+j -> row l_rel=8g+4hl+j) -> two stage-2
// A-fragments (lane=row i, halves l_rel 16c+8hl+0..7) in registers: 8 cvt + 4 permlane.
static __device__ __forceinline__ void exchange(const f32x16 &dd, half8 &f0, half8 &f1) {
    unsigned A0 = pkrtz(dd[0],  dd[1]),  B0 = pkrtz(dd[2],  dd[3]);
    unsigned A1 = pkrtz(dd[4],  dd[5]),  B1 = pkrtz(dd[6],  dd[7]);
    unsigned A2 = pkrtz(dd[8],  dd[9]),  B2 = pkrtz(dd[10], dd[11]);
    unsigned A3 = pkrtz(dd[12], dd[13]), B3 = pkrtz(dd[14], dd[15]);
    plswap(A0, A1);
    plswap(B0, B1);
    plswap(A2, A3);
    plswap(B2, B3);
    H8 h0; h0.u[0] = A0; h0.u[1] = B0; h0.u[2] = A1; h0.u[3] = B1; f0 = h0.h;
    H8 h1; h1.u[0] = A2; h1.u[1] = B2; h1.u[2] = A3; h1.u[3] = B3; f1 = h1.h;
}

// One kraus step — ROUND-6 BODY VERBATIM (best measured). All K operands from
// L1/L2 (fragment order). 64 MFMAs, 16 coalesced dwordx4 loads.
template<int IT>
static __device__ __forceinline__ void kstep(
    const _Float16* __restrict__ kb,     // this k: [plane][ihalf][slot][l31][8]
    const half8 (&a1re)[2][4], const half8 (&a1im)[2][4],
    f32x16 (&accRe)[2], f32x16 (&accIm)[2],
    int lane)
{
    const _Float16* bo = kb + IT * 2048;          // own half (stage1 B + stage2 mt=IT)
    const _Float16* bx = kb + (1 - IT) * 2048;    // other half (stage2 mt=1-IT)

    half8 bre[4], bim[4];
    #pragma unroll
    for (int ks = 0; ks < 4; ++ks) {
        bre[ks] = *(const half8*)(bo + ks * 512 + lane * 8);
        bim[ks] = *(const half8*)(bo + 4096 + ks * 512 + lane * 8);
    }

    #pragma unroll
    for (int lh = 0; lh < 2; ++lh) {
        f32x16 ddre, ddim;
        #pragma unroll
        for (int i = 0; i < 16; ++i) { ddre[i] = 0.f; ddim[i] = 0.f; }
        __builtin_amdgcn_s_setprio(1);
        #pragma unroll
        for (int ks = 0; ks < 4; ++ks) {
            half8 bn = neg8(bim[ks]);
            ddre = MFMA(a1re[lh][ks], bre[ks], ddre, 0, 0, 0);
            ddre = MFMA(a1im[lh][ks], bn,      ddre, 0, 0, 0);
            ddim = MFMA(a1re[lh][ks], bim[ks], ddim, 0, 0, 0);
            ddim = MFMA(a1im[lh][ks], bre[ks], ddim, 0, 0, 0);
        }
        __builtin_amdgcn_s_setprio(0);

        // other-half B for this lh's two l-slices: issue before exchange (latency hides)
        half8 br2[2], bi2[2];
        #pragma unroll
        for (int c = 0; c < 2; ++c) {
            const int ks = 2 * lh + c;
            br2[c] = *(const half8*)(bx + ks * 512 + lane * 8);
            bi2[c] = *(const half8*)(bx + 4096 + ks * 512 + lane * 8);
        }

        half8 fre0, fre1, fim0, fim1;
        exchange(ddre, fre0, fre1);
        exchange(ddim, fim0, fim1);

        #pragma unroll
        for (int c = 0; c < 2; ++c) {
            const int ks = 2 * lh + c;
            half8 afre = c ? fre1 : fre0;
            half8 afim = c ? fim1 : fim0;
            half8 an  = neg8(afre);
            __builtin_amdgcn_s_setprio(1);
            accRe[IT]     = MFMA(afre, bre[ks], accRe[IT], 0, 0, 0);
            accRe[IT]     = MFMA(afim, bim[ks], accRe[IT], 0, 0, 0);
            accIm[IT]     = MFMA(afim, bre[ks], accIm[IT], 0, 0, 0);
            accIm[IT]     = MFMA(an,   bim[ks], accIm[IT], 0, 0, 0);
            accRe[1 - IT] = MFMA(afre, br2[c],  accRe[1 - IT], 0, 0, 0);
            accRe[1 - IT] = MFMA(afim, bi2[c],  accRe[1 - IT], 0, 0, 0);
            accIm[1 - IT] = MFMA(afim, br2[c],  accIm[1 - IT], 0, 0, 0);
            accIm[1 - IT] = MFMA(an,   bi2[c],  accIm[1 - IT], 0, 0, 0);  // Im -= Tre*Kim
            __builtin_amdgcn_s_setprio(0);
        }
    }
}

// All 8 layers fused: rho lives in LDS (2 x 16 KB ping-pong), never returns to global
// between layers. Block = 128 threads = 2 waves (IT = wave id); grid = NB. Per layer:
// hoist a1 from LDS[l&1] -> 16 ksteps (r6 body) -> boundary write to LDS[(l+1)&1]
// (r6's proven fragment-order epilogue offsets) -> one barrier. Last layer -> global.
__global__ __launch_bounds__(128, 2) void mega_kernel(
    const _Float16* __restrict__ rho_in,    // fragment-order rho^T, [b][plane][4096]
    float* __restrict__ final_out,
    const _Float16* __restrict__ kraus)     // all layers, fragment order
{
    __shared__ __align__(16) _Float16 Rlds[2][2 * D * D];   // 32 KB

    const int b    = blockIdx.x;
    const int t    = threadIdx.x;
    const int IT   = t >> 6;
    const int lane = t & 63;
    const int l31  = lane & 31;
    const int hl   = lane >> 5;

    // ---- prologue: stage rho^T into Rlds[0] (each wave 8 KB, linear GLDS) ----
    {
        const char* rb = (const char*)(rho_in + (size_t)b * 2 * D * D);
        const int off = IT * 8192;
        #pragma unroll
        for (int r = 0; r < 8; ++r)
            GLDS16(rb + off + r * 1024 + lane * 16, (char*)&Rlds[0][0] + off + r * 1024);
    }
    __syncthreads();   // GLDS drained; Rlds[0] ready

    #pragma unroll 1
    for (int l = 0; l < NL; ++l) {
        // ---- hoist a1 fragments for this layer (16 x ds_read_b128, conflict-free) ----
        const _Float16* rl = &Rlds[l & 1][0];
        half8 a1re[2][4], a1im[2][4];
        #pragma unroll
        for (int lh = 0; lh < 2; ++lh)
            #pragma unroll
            for (int ks = 0; ks < 4; ++ks) {
                a1re[lh][ks] = *(const half8*)(rl + lh * 2048 + ks * 512 + lane * 8);
                a1im[lh][ks] = *(const half8*)(rl + 4096 + lh * 2048 + ks * 512 + lane * 8);
            }

        f32x16 accRe[2], accIm[2];
        #pragma unroll
        for (int mt = 0; mt < 2; ++mt)
            #pragma unroll
            for (int i = 0; i < 16; ++i) { accRe[mt][i] = 0.f; accIm[mt][i] = 0.f; }

        const _Float16* kl = kraus + (size_t)l * NKR * 2 * D * D;
        if (IT == 0) {
            #pragma unroll 1
            for (int k = 0; k < NKR; ++k)
                kstep<0>(kl + (size_t)k * 8192, a1re, a1im, accRe, accIm, lane);
        } else {
            #pragma unroll 1
            for (int k = 0; k < NKR; ++k)
                kstep<1>(kl + (size_t)k * 8192, a1re, a1im, accRe, accIm, lane);
        }

        if (l < NL - 1) {
            // ---- boundary: write rho_new^T fragment-order into the other LDS buffer.
            // acc lane=col m_rel, reg 4g+j -> row i = 32*IT + 8g + 4hl + j; offsets are
            // r6's proven global-epilogue formula, retargeted at LDS.
            _Float16* ob = &Rlds[(l + 1) & 1][0];
            #pragma unroll
            for (int mt = 0; mt < 2; ++mt) {
                #pragma unroll
                for (int g = 0; g < 4; ++g) {
                    Pack4 pr, pi;
                    #pragma unroll
                    for (int j = 0; j < 4; ++j) {
                        pr.h[j] = (_Float16)accRe[mt][4 * g + j];
                        pi.h[j] = (_Float16)accIm[mt][4 * g + j];
                    }
                    const int off = mt * 2048 + (4 * IT + g) * 256 + l31 * 8 + 4 * hl;
                    *(uint2*)(ob + off)        = pr.u;
                    *(uint2*)(ob + 4096 + off) = pi.u;
                }
            }
        } else {
            // ---- final epilogue to global f32 [2][b][i][m] ----
            float* o0 = final_out + (size_t)b * 4096;
            float* o1 = final_out + (size_t)(NB + b) * 4096;
            #pragma unroll
            for (int mt = 0; mt < 2; ++mt) {
                const int m = 32 * mt + l31;
                #pragma unroll
                for (int g = 0; g < 4; ++g) {
                    #pragma unroll
                    for (int j = 0; j < 4; ++j) {
                        const int i = 32 * IT + 8 * g + 4 * hl + j;
                        o0[i * D + m] = accRe[mt][4 * g + j];
                        o1[i * D + m] = accIm[mt][4 * g + j];
                    }
                }
            }
        }
        __syncthreads();   // boundary visible to both waves before next hoist
    }
}

extern "C" void kernel_launch(void* const* d_in, const int* in_sizes, int n_in,
                              void* d_out, int out_size, void* d_ws, size_t ws_size,
                              hipStream_t stream) {
    const float* state_re = (const float*)d_in[0];
    const float* state_im = (const float*)d_in[1];
    const float* kraus_re = (const float*)d_in[2];
    const float* kraus_im = (const float*)d_in[3];

    _Float16* kraus_h = (_Float16*)d_ws;                 // 2 MB in ws (frag order)
    // staging rho buffer lives at the front of d_out; mega reads it (per-block) before
    // overwriting the same per-block byte range with the final f32 output.
    _Float16* bufA = (_Float16*)d_out;
    float* fout = (float*)d_out;

    kconv_kernel<<<dim3(512, 2), 256, 0, stream>>>(kraus_re, kraus_im, kraus_h);
    sconv_kernel<<<NB, 256, 0, stream>>>(state_re, state_im, bufA);
    mega_kernel<<<NB, 128, 0, stream>>>(bufA, fout, kraus_h);
}